// Round 1
// baseline (294.085 us; speedup 1.0000x reference)
//
#include <hip/hip_runtime.h>
#include <stdint.h>

#define NN 8192
#define CC 128
#define TT 512
#define LL 30
#define CAP 64

typedef unsigned int uint32;
typedef unsigned short u16;

typedef float f32x4 __attribute__((ext_vector_type(4)));
typedef short bf16x8 __attribute__((ext_vector_type(8)));

__device__ __forceinline__ float bf2f(uint32 h) { return __uint_as_float(h << 16); }
__device__ __forceinline__ u16 f2bf(float f) {
    uint32 u = __float_as_uint(f);
    u = (u + 0x7fffu + ((u >> 16) & 1u)) >> 16;
    return (u16)u;
}

// ---------------- adjacency scan: binary dense -> per-row index list ----------------
__global__ __launch_bounds__(256) void k_adj(const float* __restrict__ adj,
                                             int* __restrict__ nbr, int* __restrict__ cnt) {
    int row = blockIdx.x * 4 + (threadIdx.x >> 6);
    int lane = threadIdx.x & 63;
    if (row >= NN) return;
    const float4* arow = (const float4*)(adj + (size_t)row * NN);
    int base = 0;
    int* dst = nbr + (size_t)row * CAP;
    for (int it = 0; it < 32; ++it) {
        float4 v = arow[it * 64 + lane];
        float vv[4] = {v.x, v.y, v.z, v.w};
#pragma unroll
        for (int j = 0; j < 4; ++j) {
            unsigned long long m = __ballot(vv[j] != 0.f);
            if (vv[j] != 0.f) {
                int pos = base + __popcll(m & ((1ull << lane) - 1ull));
                if (pos < CAP) dst[pos] = it * 256 + lane * 4 + j;
            }
            base += __popcll(m);
        }
    }
    if (lane == 0) cnt[row] = base < CAP ? base : CAP;
}

// ---------------- W fragment packing + x0 -> bf16 ----------------
__global__ __launch_bounds__(256) void k_prep(
    const float* __restrict__ W1r, const float* __restrict__ W1s,
    const float* __restrict__ W2r, const float* __restrict__ W2s,
    const float* __restrict__ W3r, const float* __restrict__ W3s,
    const float* __restrict__ Wl, const float* __restrict__ x0,
    u16* __restrict__ wfrag, u16* __restrict__ x0bf) {
    int b = blockIdx.x, tid = threadIdx.x;
    if (b < 288) {
        const float* Wa;
        const float* Wb;
        int tile, gbase;
        if (b < 64)       { Wa = W1r; Wb = W1s; tile = b;       gbase = 0; }
        else if (b < 128) { Wa = W2r; Wb = W2s; tile = b - 64;  gbase = 64; }
        else if (b < 192) { Wa = W3r; Wb = W3s; tile = b - 128; gbase = 128; }
        else              { Wa = Wl;  Wb = nullptr; tile = b - 192; gbase = 192; }
        int kt = tile >> 3, nt = tile & 7;
        int lane = tid & 63, i0 = (tid >> 6) * 2;
        int n = nt * 16 + (lane & 15);
        u16* dst = wfrag + ((size_t)(gbase + tile) * 64 + lane) * 8;
#pragma unroll
        for (int ii = 0; ii < 2; ++ii) {
            int i = i0 + ii;
            int k = kt * 32 + ((lane >> 4) * 8) + i;
            float v;
            if (Wb) v = (k < 128) ? Wa[k * CC + n] : Wb[(k - 128) * CC + n];
            else    v = Wa[k * CC + n];
            dst[i] = f2bf(v);
        }
    } else {
        int idx = (b - 288) * 1024 + tid * 4;
        float4 v = *(const float4*)(x0 + idx);
        ushort4 o;
        o.x = f2bf(v.x); o.y = f2bf(v.y); o.z = f2bf(v.z); o.w = f2bf(v.w);
        *(ushort4*)(x0bf + idx) = o;
    }
}

// ---------------- fused [aggregate]+GEMM(+bias,relu)+[BN partial stats] ----------------
// AGG=true : A = [gather-sum(ch0) | ch0], K = 256 (KT=8), writes BN partials
// AGG=false: A = [ch0 | ch1 | ch2],       K = 384 (KT=12)
template <int KT, bool AGG>
__global__ __launch_bounds__(256) void k_gemm(
    const u16* __restrict__ ch0, const u16* __restrict__ ch1, const u16* __restrict__ ch2,
    const int* __restrict__ nbr, const int* __restrict__ cnt,
    const u16* __restrict__ wfrag, const float* __restrict__ bias,
    float* __restrict__ outp, int ostride, float* __restrict__ partials) {
    constexpr int KW = KT * 32 + 8;  // +8 bf16 pad -> 2-way LDS conflicts only
    __shared__ u16 A[32][KW];
    __shared__ float sSum[CC], sSq[CC];
    int tid = threadIdx.x, lane = tid & 63, wid = tid >> 6;
    int row0 = blockIdx.x * 32;

    if constexpr (AGG) {
        if (tid < CC) { sSum[tid] = 0.f; sSq[tid] = 0.f; }
        int c = lane * 2;
        for (int r = wid; r < 32; r += 4) {
            int grow = row0 + r;
            int nn = cnt[grow];
            const int* nb = nbr + (size_t)grow * CAP;
            float a0 = 0.f, a1 = 0.f;
            for (int j = 0; j < nn; ++j) {
                int m = nb[j];
                uint32 v = *(const uint32*)(ch0 + (size_t)m * CC + c);
                a0 += bf2f(v & 0xffffu);
                a1 += bf2f(v >> 16);
            }
            uint32 pk = (uint32)f2bf(a0) | ((uint32)f2bf(a1) << 16);
            *(uint32*)&A[r][c] = pk;
            *(uint32*)&A[r][CC + c] = *(const uint32*)(ch0 + (size_t)grow * CC + c);
        }
    } else {
        constexpr int CH = KT * 4;  // 8-bf16 chunks per row
        for (int cc = tid; cc < 32 * CH; cc += 256) {
            int r = cc / CH;
            int k = (cc % CH) * 8;
            const u16* src;
            if (k < 128)      src = ch0 + (size_t)(row0 + r) * CC + k;
            else if (k < 256) src = ch1 + (size_t)(row0 + r) * CC + (k - 128);
            else              src = ch2 + (size_t)(row0 + r) * CC + (k - 256);
            *(uint4*)&A[r][k] = *(const uint4*)src;
        }
    }
    __syncthreads();

    int mh = wid >> 1, nh = wid & 1;
    int arow = mh * 16 + (lane & 15);
    int kg = (lane >> 4) * 8;
    f32x4 acc[4];
#pragma unroll
    for (int nt = 0; nt < 4; ++nt) acc[nt] = (f32x4){0.f, 0.f, 0.f, 0.f};
#pragma unroll
    for (int kt = 0; kt < KT; ++kt) {
        bf16x8 a = *(const bf16x8*)&A[arow][kt * 32 + kg];
        const u16* wb = wfrag + ((size_t)(kt * 8 + nh * 4) * 64 + lane) * 8;
#pragma unroll
        for (int nt = 0; nt < 4; ++nt) {
            bf16x8 bfr = *(const bf16x8*)(wb + (size_t)nt * 512);
            acc[nt] = __builtin_amdgcn_mfma_f32_16x16x32_bf16(a, bfr, acc[nt], 0, 0, 0);
        }
    }
    int rowb = row0 + mh * 16 + ((lane >> 4) * 4);
#pragma unroll
    for (int nt = 0; nt < 4; ++nt) {
        int col = nh * 64 + nt * 16 + (lane & 15);
        float bv = bias[col];
        float s1 = 0.f, s2 = 0.f;
#pragma unroll
        for (int q = 0; q < 4; ++q) {
            float y = acc[nt][q] + bv;
            y = y > 0.f ? y : 0.f;
            outp[(size_t)(rowb + q) * ostride + col] = y;
            s1 += y;
            s2 += y * y;
        }
        if constexpr (AGG) {
            s1 += __shfl_xor(s1, 16); s1 += __shfl_xor(s1, 32);
            s2 += __shfl_xor(s2, 16); s2 += __shfl_xor(s2, 32);
            if ((lane >> 4) == 0) { atomicAdd(&sSum[col], s1); atomicAdd(&sSq[col], s2); }
        }
    }
    if constexpr (AGG) {
        __syncthreads();
        if (tid < CC) {
            partials[(size_t)blockIdx.x * 256 + tid] = sSum[tid];
            partials[(size_t)blockIdx.x * 256 + CC + tid] = sSq[tid];
        }
    }
}

// ---------------- BN stats finalize -> affine coef ----------------
__global__ __launch_bounds__(256) void k_stats2(const float* __restrict__ P,
                                                const float* __restrict__ g,
                                                const float* __restrict__ be,
                                                float* __restrict__ coef) {
    __shared__ float4 S[8][32], Q[8][32];
    int tid = threadIdx.x, cg = tid & 31, h = tid >> 5;
    int c = cg * 4;
    float4 s = {0, 0, 0, 0}, q = {0, 0, 0, 0};
    for (int b = h; b < 256; b += 8) {
        float4 v = *(const float4*)(P + b * 256 + c);
        float4 w = *(const float4*)(P + b * 256 + 128 + c);
        s.x += v.x; s.y += v.y; s.z += v.z; s.w += v.w;
        q.x += w.x; q.y += w.y; q.z += w.z; q.w += w.w;
    }
    S[h][cg] = s; Q[h][cg] = q;
    __syncthreads();
    if (tid < 32) {
        float4 ts = S[0][tid], tq = Q[0][tid];
#pragma unroll
        for (int i = 1; i < 8; ++i) {
            float4 v = S[i][tid], w = Q[i][tid];
            ts.x += v.x; ts.y += v.y; ts.z += v.z; ts.w += v.w;
            tq.x += w.x; tq.y += w.y; tq.z += w.z; tq.w += w.w;
        }
        int c0 = tid * 4;
        float sums[4] = {ts.x, ts.y, ts.z, ts.w};
        float sqs[4] = {tq.x, tq.y, tq.z, tq.w};
#pragma unroll
        for (int i = 0; i < 4; ++i) {
            float mu = sums[i] * (1.f / NN);
            float var = sqs[i] * (1.f / NN) - mu * mu;
            float rs = rsqrtf(var + 1e-5f);
            float a = g[c0 + i] * rs;
            coef[c0 + i] = a;
            coef[128 + c0 + i] = be[c0 + i] - mu * a;
        }
    }
}

// ---------------- normalize in-place (xcat slice) + emit bf16 copy ----------------
__global__ __launch_bounds__(256) void k_norm(float* __restrict__ y,
                                              const float* __restrict__ coef,
                                              u16* __restrict__ xbf) {
    int idx4 = blockIdx.x * 256 + threadIdx.x;
    int n = idx4 >> 5;
    int c = (idx4 & 31) * 4;
    float* p = y + (size_t)n * 384 + c;
    float4 v = *(float4*)p;
    float4 a = *(const float4*)(coef + c);
    float4 b = *(const float4*)(coef + 128 + c);
    float4 o;
    o.x = v.x * a.x + b.x; o.y = v.y * a.y + b.y;
    o.z = v.z * a.z + b.z; o.w = v.w * a.w + b.w;
    *(float4*)p = o;
    ushort4 ob;
    ob.x = f2bf(o.x); ob.y = f2bf(o.y); ob.z = f2bf(o.z); ob.w = f2bf(o.w);
    *(ushort4*)(xbf + (size_t)n * CC + c) = ob;
}

// ---------------- team / sample / remain embeddings ----------------
__device__ __forceinline__ float wave_max64(float v) {
#pragma unroll
    for (int o = 32; o > 0; o >>= 1) v = fmaxf(v, __shfl_xor(v, o));
    return v;
}
__device__ __forceinline__ float wave_sum64(float v) {
#pragma unroll
    for (int o = 32; o > 0; o >>= 1) v += __shfl_xor(v, o);
    return v;
}

__global__ __launch_bounds__(128) void k_team(
    const u16* __restrict__ x1bf, const u16* __restrict__ x2bf, const u16* __restrict__ x3bf,
    const int* __restrict__ teams, const int* __restrict__ slen_p,
    const float* __restrict__ att,
    float* __restrict__ oT, float* __restrict__ oS, float* __restrict__ oR) {
    __shared__ float wT[LL], wS[LL], wR[LL];
    __shared__ int ids[LL];
    int t = blockIdx.x, tid = threadIdx.x;
    if (tid < 64) {
        int lane = tid;
        bool act = lane < LL;
        float a = act ? att[t * LL + lane] : 0.f;
        int id = act ? teams[t * LL + lane] : NN;
        if (act) ids[lane] = id;
        int sl = *slen_p;
        const float NEG = -1e30f;
        // team: full softmax over all L entries
        float mT = wave_max64(act ? a : NEG);
        float eT = act ? __expf(a - mT) : 0.f;
        float sT = wave_sum64(eT);
        // sample: pos < sample_len
        bool inS = act && (lane < sl);
        float mS = wave_max64(inS ? a : NEG);
        float eS = inS ? __expf(a - mS) : 0.f;
        float sS = wave_sum64(eS);
        // remain: pos >= sample_len && id != pad
        bool inR = act && (lane >= sl) && (id != NN);
        float mR = wave_max64(inR ? a : NEG);
        float eR = inR ? __expf(a - mR) : 0.f;
        float sR = wave_sum64(eR);
        if (act) {
            wT[lane] = eT / sT;
            wS[lane] = eS / sS;
            wR[lane] = eR / sR;
        }
    }
    __syncthreads();
#pragma unroll
    for (int seg = 0; seg < 3; ++seg) {
        int d = seg * 128 + tid;
        const u16* xb = seg == 0 ? x1bf : seg == 1 ? x2bf : x3bf;
        float aT = 0.f, aS = 0.f, aR = 0.f;
        for (int l = 0; l < LL; ++l) {
            int id = ids[l];
            if (id < NN) {
                float v = bf2f((uint32)xb[(size_t)id * CC + tid]);
                aT += wT[l] * v;
                aS += wS[l] * v;
                aR += wR[l] * v;
            }
        }
        oT[(size_t)t * 384 + d] = aT;
        oS[(size_t)t * 384 + d] = aS;
        oR[(size_t)t * 384 + d] = aR;
    }
}

extern "C" void kernel_launch(void* const* d_in, const int* in_sizes, int n_in,
                              void* d_out, int out_size, void* d_ws, size_t ws_size,
                              hipStream_t stream) {
    const float* x = (const float*)d_in[0];
    const float* adj = (const float*)d_in[1];
    const int* teams = (const int*)d_in[2];
    const int* slen = (const int*)d_in[3];
    const float* W1r = (const float*)d_in[4];
    const float* b1 = (const float*)d_in[5];
    const float* W1s = (const float*)d_in[6];
    const float* W2r = (const float*)d_in[7];
    const float* b2 = (const float*)d_in[8];
    const float* W2s = (const float*)d_in[9];
    const float* W3r = (const float*)d_in[10];
    const float* b3 = (const float*)d_in[11];
    const float* W3s = (const float*)d_in[12];
    const float* g1 = (const float*)d_in[13];
    const float* be1 = (const float*)d_in[14];
    const float* g2 = (const float*)d_in[15];
    const float* be2 = (const float*)d_in[16];
    const float* g3 = (const float*)d_in[17];
    const float* be3 = (const float*)d_in[18];
    const float* Wl = (const float*)d_in[19];
    const float* bl = (const float*)d_in[20];
    const float* att = (const float*)d_in[21];

    float* out = (float*)d_out;
    float* s_out = out;
    float* xcat = out + (size_t)NN * CC;
    float* oT = xcat + (size_t)NN * 384;
    float* oS = oT + (size_t)TT * 384;
    float* oR = oS + (size_t)TT * 384;

    char* ws = (char*)d_ws;
    size_t off = 0;
    int* nbr = (int*)(ws + off); off += (size_t)NN * CAP * 4;
    int* cnt = (int*)(ws + off); off += (size_t)NN * 4;
    u16* x0bf = (u16*)(ws + off); off += (size_t)NN * CC * 2;
    u16* x1bf = (u16*)(ws + off); off += (size_t)NN * CC * 2;
    u16* x2bf = (u16*)(ws + off); off += (size_t)NN * CC * 2;
    u16* x3bf = (u16*)(ws + off); off += (size_t)NN * CC * 2;
    u16* wfrag = (u16*)(ws + off); off += (size_t)288 * 512 * 2;
    float* partials = (float*)(ws + off); off += (size_t)256 * 256 * 4;
    float* coef = (float*)(ws + off); off += 256 * 4;

    k_adj<<<2048, 256, 0, stream>>>(adj, nbr, cnt);
    k_prep<<<1312, 256, 0, stream>>>(W1r, W1s, W2r, W2s, W3r, W3s, Wl, x, wfrag, x0bf);

    // layer 1
    k_gemm<8, true><<<256, 256, 0, stream>>>(x0bf, nullptr, nullptr, nbr, cnt,
                                             wfrag, b1, xcat + 0, 384, partials);
    k_stats2<<<1, 256, 0, stream>>>(partials, g1, be1, coef);
    k_norm<<<1024, 256, 0, stream>>>(xcat + 0, coef, x1bf);
    // layer 2
    k_gemm<8, true><<<256, 256, 0, stream>>>(x1bf, nullptr, nullptr, nbr, cnt,
                                             wfrag + 64 * 512, b2, xcat + 128, 384, partials);
    k_stats2<<<1, 256, 0, stream>>>(partials, g2, be2, coef);
    k_norm<<<1024, 256, 0, stream>>>(xcat + 128, coef, x2bf);
    // layer 3
    k_gemm<8, true><<<256, 256, 0, stream>>>(x2bf, nullptr, nullptr, nbr, cnt,
                                             wfrag + 128 * 512, b3, xcat + 256, 384, partials);
    k_stats2<<<1, 256, 0, stream>>>(partials, g3, be3, coef);
    k_norm<<<1024, 256, 0, stream>>>(xcat + 256, coef, x3bf);

    // s = relu(xcat @ Wl + bl)
    k_gemm<12, false><<<256, 256, 0, stream>>>(x1bf, x2bf, x3bf, nbr, cnt,
                                               wfrag + 192 * 512, bl, s_out, 128, nullptr);
    // team embeddings
    k_team<<<512, 128, 0, stream>>>(x1bf, x2bf, x3bf, teams, slen, att, oT, oS, oR);
}

// Round 2
// 168.084 us; speedup vs baseline: 1.7496x; 1.7496x over previous
//
#include <hip/hip_runtime.h>
#include <stdint.h>

#define NN 8192
#define CC 128
#define TT 512
#define LL 30
#define CAP 64

typedef unsigned int uint32;
typedef unsigned short u16;

typedef float f32x4 __attribute__((ext_vector_type(4)));
typedef short bf16x8 __attribute__((ext_vector_type(8)));

__device__ __forceinline__ float bf2f(uint32 h) { return __uint_as_float(h << 16); }
__device__ __forceinline__ u16 f2bf(float f) {
    uint32 u = __float_as_uint(f);
    u = (u + 0x7fffu + ((u >> 16) & 1u)) >> 16;
    return (u16)u;
}
__device__ __forceinline__ uint32 pack2(float a, float b) {
    return (uint32)f2bf(a) | ((uint32)f2bf(b) << 16);
}

// ---------------- adjacency scan: binary dense -> padded per-row index list ----------------
__global__ __launch_bounds__(256) void k_adj(const float* __restrict__ adj,
                                             int* __restrict__ nbr, int* __restrict__ cnt) {
    int row = blockIdx.x * 4 + (threadIdx.x >> 6);
    int lane = threadIdx.x & 63;
    const float4* arow = (const float4*)(adj + (size_t)row * NN);
    int base = 0;
    int* dst = nbr + (size_t)row * CAP;
    for (int it = 0; it < 32; ++it) {
        float4 v = arow[it * 64 + lane];
        float vv[4] = {v.x, v.y, v.z, v.w};
#pragma unroll
        for (int j = 0; j < 4; ++j) {
            unsigned long long m = __ballot(vv[j] != 0.f);
            if (vv[j] != 0.f) {
                int pos = base + __popcll(m & ((1ull << lane) - 1ull));
                if (pos < CAP) dst[pos] = it * 256 + lane * 4 + j;
            }
            base += __popcll(m);
        }
    }
    int nn = base < CAP ? base : CAP;
    int npad = (nn + 3) & ~3;
    for (int p = nn + lane; p < npad; p += 64) dst[p] = NN;  // sentinel -> zero row
    if (lane == 0) cnt[row] = nn;
}

// ---------------- W fragment packing + x0 -> bf16 + zero rows + identity coef ----------------
__global__ __launch_bounds__(256) void k_prep(
    const float* __restrict__ W1r, const float* __restrict__ W1s,
    const float* __restrict__ W2r, const float* __restrict__ W2s,
    const float* __restrict__ W3r, const float* __restrict__ W3s,
    const float* __restrict__ Wl, const float* __restrict__ x0,
    u16* __restrict__ wfrag, u16* __restrict__ x0bf,
    u16* __restrict__ yp1, u16* __restrict__ yp2, u16* __restrict__ yp3,
    float* __restrict__ coefs) {
    int b = blockIdx.x, tid = threadIdx.x;
    if (b < 288) {
        const float* Wa;
        const float* Wb;
        int tile, gbase;
        if (b < 64)       { Wa = W1r; Wb = W1s; tile = b;       gbase = 0; }
        else if (b < 128) { Wa = W2r; Wb = W2s; tile = b - 64;  gbase = 64; }
        else if (b < 192) { Wa = W3r; Wb = W3s; tile = b - 128; gbase = 128; }
        else              { Wa = Wl;  Wb = nullptr; tile = b - 192; gbase = 192; }
        int kt = tile >> 3, nt = tile & 7;
        int lane = tid & 63, i0 = (tid >> 6) * 2;
        int n = nt * 16 + (lane & 15);
        u16* dst = wfrag + ((size_t)(gbase + tile) * 64 + lane) * 8;
#pragma unroll
        for (int ii = 0; ii < 2; ++ii) {
            int i = i0 + ii;
            int k = kt * 32 + ((lane >> 4) * 8) + i;
            float v;
            if (Wb) v = (k < 128) ? Wa[k * CC + n] : Wb[(k - 128) * CC + n];
            else    v = Wa[k * CC + n];
            dst[i] = f2bf(v);
        }
    } else if (b < 1312) {
        int idx = (b - 288) * 1024 + tid * 4;
        const float* src = x0 + idx;
        float4 v = *(const float4*)src;
        ushort4 o;
        o.x = f2bf(v.x); o.y = f2bf(v.y); o.z = f2bf(v.z); o.w = f2bf(v.w);
        *(ushort4*)(x0bf + idx) = o;
    } else {
        if (tid < 128) {
            x0bf[(size_t)NN * CC + tid] = 0;
            yp1[(size_t)NN * CC + tid] = 0;
            yp2[(size_t)NN * CC + tid] = 0;
            yp3[(size_t)NN * CC + tid] = 0;
            coefs[tid] = 1.f;        // layer-0 identity affine
            coefs[128 + tid] = 0.f;
        }
    }
}

// ---------------- aggregation: Ab[row] = [a*sum_nbr(src)+b*n | a*src[row]+b] ----------------
__global__ __launch_bounds__(256) void k_agg(const u16* __restrict__ src,
                                             const float* __restrict__ coef,
                                             const int* __restrict__ nbr,
                                             const int* __restrict__ cnt,
                                             u16* __restrict__ Ab) {
    int row = blockIdx.x * 4 + (threadIdx.x >> 6);
    int lane = threadIdx.x & 63;
    int c = lane * 2;
    int nreal = cnt[row];
    int npad = (nreal + 3) & ~3;
    const int* nb = nbr + (size_t)row * CAP;
    float a0 = 0.f, a1 = 0.f;
    for (int j = 0; j < npad; j += 4) {
        int4 m = *(const int4*)(nb + j);
        uint32 v0 = *(const uint32*)(src + (size_t)m.x * CC + c);
        uint32 v1 = *(const uint32*)(src + (size_t)m.y * CC + c);
        uint32 v2 = *(const uint32*)(src + (size_t)m.z * CC + c);
        uint32 v3 = *(const uint32*)(src + (size_t)m.w * CC + c);
        a0 += bf2f(v0 & 0xffffu); a1 += bf2f(v0 >> 16);
        a0 += bf2f(v1 & 0xffffu); a1 += bf2f(v1 >> 16);
        a0 += bf2f(v2 & 0xffffu); a1 += bf2f(v2 >> 16);
        a0 += bf2f(v3 & 0xffffu); a1 += bf2f(v3 >> 16);
    }
    float ca0 = coef[c], ca1 = coef[c + 1];
    float cb0 = coef[128 + c], cb1 = coef[128 + c + 1];
    float fn = (float)nreal;
    uint32 rv = *(const uint32*)(src + (size_t)row * CC + c);
    u16* dst = Ab + (size_t)row * 256;
    *(uint32*)(dst + c) = pack2(ca0 * a0 + cb0 * fn, ca1 * a1 + cb1 * fn);
    *(uint32*)(dst + 128 + c) = pack2(ca0 * bf2f(rv & 0xffffu) + cb0,
                                      ca1 * bf2f(rv >> 16) + cb1);
}

// ---------------- layer GEMM: yp = relu(Ab @ [Wr;Ws] + b), + BN partial stats ----------------
__global__ __launch_bounds__(256) void k_gemm(const u16* __restrict__ Ab,
                                              const u16* __restrict__ wfrag,
                                              const float* __restrict__ bias,
                                              u16* __restrict__ yp,
                                              float* __restrict__ partials) {
    __shared__ u16 A[32][264];  // +8 pad
    __shared__ float sSum[CC], sSq[CC];
    int tid = threadIdx.x, lane = tid & 63, wid = tid >> 6;
    int row0 = blockIdx.x * 32;
    if (tid < CC) { sSum[tid] = 0.f; sSq[tid] = 0.f; }
    for (int i = tid; i < 1024; i += 256) {
        int r = i >> 5, k = (i & 31) * 8;
        *(uint4*)&A[r][k] = *(const uint4*)(Ab + (size_t)(row0 + r) * 256 + k);
    }
    __syncthreads();

    int mh = wid >> 1, nh = wid & 1;
    int arow = mh * 16 + (lane & 15);
    int kg = (lane >> 4) * 8;
    f32x4 acc[4];
#pragma unroll
    for (int nt = 0; nt < 4; ++nt) acc[nt] = (f32x4){0.f, 0.f, 0.f, 0.f};
#pragma unroll
    for (int kt = 0; kt < 8; ++kt) {
        bf16x8 a = *(const bf16x8*)&A[arow][kt * 32 + kg];
        const u16* wb = wfrag + ((size_t)(kt * 8 + nh * 4) * 64 + lane) * 8;
#pragma unroll
        for (int nt = 0; nt < 4; ++nt) {
            bf16x8 bfr = *(const bf16x8*)(wb + (size_t)nt * 512);
            acc[nt] = __builtin_amdgcn_mfma_f32_16x16x32_bf16(a, bfr, acc[nt], 0, 0, 0);
        }
    }
    int rowb = row0 + mh * 16 + ((lane >> 4) * 4);
#pragma unroll
    for (int nt = 0; nt < 4; ++nt) {
        int col = nh * 64 + nt * 16 + (lane & 15);
        float bv = bias[col];
        float s1 = 0.f, s2 = 0.f;
#pragma unroll
        for (int q = 0; q < 4; ++q) {
            float y = acc[nt][q] + bv;
            y = y > 0.f ? y : 0.f;
            yp[(size_t)(rowb + q) * CC + col] = f2bf(y);
            s1 += y;
            s2 += y * y;
        }
        s1 += __shfl_xor(s1, 16); s1 += __shfl_xor(s1, 32);
        s2 += __shfl_xor(s2, 16); s2 += __shfl_xor(s2, 32);
        if ((lane >> 4) == 0) { atomicAdd(&sSum[col], s1); atomicAdd(&sSq[col], s2); }
    }
    __syncthreads();
    if (tid < CC) {
        partials[(size_t)blockIdx.x * 256 + tid] = sSum[tid];
        partials[(size_t)blockIdx.x * 256 + CC + tid] = sSq[tid];
    }
}

// ---------------- BN stats finalize -> affine coef ----------------
__global__ __launch_bounds__(256) void k_stats2(const float* __restrict__ P,
                                                const float* __restrict__ g,
                                                const float* __restrict__ be,
                                                float* __restrict__ coef) {
    __shared__ float4 S[8][32], Q[8][32];
    int tid = threadIdx.x, cg = tid & 31, h = tid >> 5;
    int c = cg * 4;
    float4 s = {0, 0, 0, 0}, q = {0, 0, 0, 0};
    for (int b = h; b < 256; b += 8) {
        float4 v = *(const float4*)(P + b * 256 + c);
        float4 w = *(const float4*)(P + b * 256 + 128 + c);
        s.x += v.x; s.y += v.y; s.z += v.z; s.w += v.w;
        q.x += w.x; q.y += w.y; q.z += w.z; q.w += w.w;
    }
    S[h][cg] = s; Q[h][cg] = q;
    __syncthreads();
    if (tid < 32) {
        float4 ts = S[0][tid], tq = Q[0][tid];
#pragma unroll
        for (int i = 1; i < 8; ++i) {
            float4 v = S[i][tid], w = Q[i][tid];
            ts.x += v.x; ts.y += v.y; ts.z += v.z; ts.w += v.w;
            tq.x += w.x; tq.y += w.y; tq.z += w.z; tq.w += w.w;
        }
        int c0 = tid * 4;
        float sums[4] = {ts.x, ts.y, ts.z, ts.w};
        float sqs[4] = {tq.x, tq.y, tq.z, tq.w};
#pragma unroll
        for (int i = 0; i < 4; ++i) {
            float mu = sums[i] * (1.f / NN);
            float var = sqs[i] * (1.f / NN) - mu * mu;
            float rs = rsqrtf(var + 1e-5f);
            float a = g[c0 + i] * rs;
            coef[c0 + i] = a;
            coef[128 + c0 + i] = be[c0 + i] - mu * a;
        }
    }
}

// ---------------- final linear: s = relu([x1n|x2n|x3n] @ Wl + bl) ----------------
__global__ __launch_bounds__(256) void k_gfinal(const u16* __restrict__ yp1,
                                                const u16* __restrict__ yp2,
                                                const u16* __restrict__ yp3,
                                                const float* __restrict__ coefs,  // [3][256]
                                                const u16* __restrict__ wfrag,
                                                const float* __restrict__ bias,
                                                float* __restrict__ sout) {
    __shared__ u16 A[32][392];  // 384 + 8 pad
    int tid = threadIdx.x, lane = tid & 63, wid = tid >> 6;
    int row0 = blockIdx.x * 32;
    for (int i = tid; i < 1536; i += 256) {
        int r = i / 48, kk = (i % 48) * 8;
        int seg = kk >> 7, c = kk & 127;
        const u16* sp = (seg == 0 ? yp1 : seg == 1 ? yp2 : yp3) + (size_t)(row0 + r) * CC + c;
        uint4 raw = *(const uint4*)sp;
        const float* cf = coefs + seg * 256;
        float4 av0 = *(const float4*)(cf + c);
        float4 av1 = *(const float4*)(cf + c + 4);
        float4 bv0 = *(const float4*)(cf + 128 + c);
        float4 bv1 = *(const float4*)(cf + 128 + c + 4);
        uint32 w0 = raw.x, w1 = raw.y, w2 = raw.z, w3 = raw.w;
        uint4 o;
        o.x = pack2(av0.x * bf2f(w0 & 0xffffu) + bv0.x, av0.y * bf2f(w0 >> 16) + bv0.y);
        o.y = pack2(av0.z * bf2f(w1 & 0xffffu) + bv0.z, av0.w * bf2f(w1 >> 16) + bv0.w);
        o.z = pack2(av1.x * bf2f(w2 & 0xffffu) + bv1.x, av1.y * bf2f(w2 >> 16) + bv1.y);
        o.w = pack2(av1.z * bf2f(w3 & 0xffffu) + bv1.z, av1.w * bf2f(w3 >> 16) + bv1.w);
        *(uint4*)&A[r][kk] = o;
    }
    __syncthreads();

    int mh = wid >> 1, nh = wid & 1;
    int arow = mh * 16 + (lane & 15);
    int kg = (lane >> 4) * 8;
    f32x4 acc[4];
#pragma unroll
    for (int nt = 0; nt < 4; ++nt) acc[nt] = (f32x4){0.f, 0.f, 0.f, 0.f};
#pragma unroll
    for (int kt = 0; kt < 12; ++kt) {
        bf16x8 a = *(const bf16x8*)&A[arow][kt * 32 + kg];
        const u16* wb = wfrag + ((size_t)(kt * 8 + nh * 4) * 64 + lane) * 8;
#pragma unroll
        for (int nt = 0; nt < 4; ++nt) {
            bf16x8 bfr = *(const bf16x8*)(wb + (size_t)nt * 512);
            acc[nt] = __builtin_amdgcn_mfma_f32_16x16x32_bf16(a, bfr, acc[nt], 0, 0, 0);
        }
    }
    int rowb = row0 + mh * 16 + ((lane >> 4) * 4);
#pragma unroll
    for (int nt = 0; nt < 4; ++nt) {
        int col = nh * 64 + nt * 16 + (lane & 15);
        float bv = bias[col];
#pragma unroll
        for (int q = 0; q < 4; ++q) {
            float y = acc[nt][q] + bv;
            sout[(size_t)(rowb + q) * CC + col] = y > 0.f ? y : 0.f;
        }
    }
}

// ---------------- team / sample / remain embeddings ----------------
__device__ __forceinline__ float wave_max64(float v) {
#pragma unroll
    for (int o = 32; o > 0; o >>= 1) v = fmaxf(v, __shfl_xor(v, o));
    return v;
}
__device__ __forceinline__ float wave_sum64(float v) {
#pragma unroll
    for (int o = 32; o > 0; o >>= 1) v += __shfl_xor(v, o);
    return v;
}

__global__ __launch_bounds__(128) void k_team(
    const u16* __restrict__ yp1, const u16* __restrict__ yp2, const u16* __restrict__ yp3,
    const float* __restrict__ coefs,  // [3][256]
    const int* __restrict__ teams, const int* __restrict__ slen_p,
    const float* __restrict__ att,
    float* __restrict__ oT, float* __restrict__ oS, float* __restrict__ oR) {
    __shared__ float wT[LL], wS[LL], wR[LL];
    __shared__ int ids[LL];
    int t = blockIdx.x, tid = threadIdx.x;
    if (tid < 64) {
        int lane = tid;
        bool act = lane < LL;
        float a = act ? att[t * LL + lane] : 0.f;
        int id = act ? teams[t * LL + lane] : NN;
        if (act) ids[lane] = id;
        int sl = *slen_p;
        const float NEG = -1e30f;
        float mT = wave_max64(act ? a : NEG);
        float eT = act ? __expf(a - mT) : 0.f;
        float sT = wave_sum64(eT);
        bool inS = act && (lane < sl);
        float mS = wave_max64(inS ? a : NEG);
        float eS = inS ? __expf(a - mS) : 0.f;
        float sS = wave_sum64(eS);
        bool inR = act && (lane >= sl) && (id != NN);
        float mR = wave_max64(inR ? a : NEG);
        float eR = inR ? __expf(a - mR) : 0.f;
        float sR = wave_sum64(eR);
        if (act) {
            wT[lane] = eT / sT;
            wS[lane] = eS / sS;
            wR[lane] = eR / sR;
        }
    }
    __syncthreads();
#pragma unroll
    for (int seg = 0; seg < 3; ++seg) {
        int d = seg * 128 + tid;
        const u16* xb = seg == 0 ? yp1 : seg == 1 ? yp2 : yp3;
        float ca = coefs[seg * 256 + tid];
        float cb = coefs[seg * 256 + 128 + tid];
        float aT = 0.f, aS = 0.f, aR = 0.f;
        for (int l = 0; l < LL; ++l) {
            int id = ids[l];
            if (id < NN) {
                float v = ca * bf2f((uint32)xb[(size_t)id * CC + tid]) + cb;
                aT += wT[l] * v;
                aS += wS[l] * v;
                aR += wR[l] * v;
            }
        }
        oT[(size_t)t * 384 + d] = aT;
        oS[(size_t)t * 384 + d] = aS;
        oR[(size_t)t * 384 + d] = aR;
    }
}

// ---------------- xcat f32 output: normalize yp1..3 with coefs ----------------
__global__ __launch_bounds__(256) void k_normcat(const u16* __restrict__ yp1,
                                                 const u16* __restrict__ yp2,
                                                 const u16* __restrict__ yp3,
                                                 const float* __restrict__ coefs,
                                                 float* __restrict__ xcat) {
    int idx = blockIdx.x * 256 + threadIdx.x;  // one per 4 f32
    int n = idx / 96;
    int k = (idx % 96) * 4;
    int seg = k >> 7, c = k & 127;
    const u16* sp = (seg == 0 ? yp1 : seg == 1 ? yp2 : yp3) + (size_t)n * CC + c;
    ushort4 raw = *(const ushort4*)sp;
    const float* cf = coefs + seg * 256;
    float4 a = *(const float4*)(cf + c);
    float4 b = *(const float4*)(cf + 128 + c);
    float4 o;
    o.x = a.x * bf2f((uint32)raw.x) + b.x;
    o.y = a.y * bf2f((uint32)raw.y) + b.y;
    o.z = a.z * bf2f((uint32)raw.z) + b.z;
    o.w = a.w * bf2f((uint32)raw.w) + b.w;
    *(float4*)(xcat + (size_t)n * 384 + k) = o;
}

extern "C" void kernel_launch(void* const* d_in, const int* in_sizes, int n_in,
                              void* d_out, int out_size, void* d_ws, size_t ws_size,
                              hipStream_t stream) {
    const float* x = (const float*)d_in[0];
    const float* adj = (const float*)d_in[1];
    const int* teams = (const int*)d_in[2];
    const int* slen = (const int*)d_in[3];
    const float* W1r = (const float*)d_in[4];
    const float* b1 = (const float*)d_in[5];
    const float* W1s = (const float*)d_in[6];
    const float* W2r = (const float*)d_in[7];
    const float* b2 = (const float*)d_in[8];
    const float* W2s = (const float*)d_in[9];
    const float* W3r = (const float*)d_in[10];
    const float* b3 = (const float*)d_in[11];
    const float* W3s = (const float*)d_in[12];
    const float* g1 = (const float*)d_in[13];
    const float* be1 = (const float*)d_in[14];
    const float* g2 = (const float*)d_in[15];
    const float* be2 = (const float*)d_in[16];
    const float* g3 = (const float*)d_in[17];
    const float* be3 = (const float*)d_in[18];
    const float* Wl = (const float*)d_in[19];
    const float* bl = (const float*)d_in[20];
    const float* att = (const float*)d_in[21];

    float* out = (float*)d_out;
    float* s_out = out;
    float* xcat = out + (size_t)NN * CC;
    float* oT = xcat + (size_t)NN * 384;
    float* oS = oT + (size_t)TT * 384;
    float* oR = oS + (size_t)TT * 384;

    char* ws = (char*)d_ws;
    size_t off = 0;
    int* nbr = (int*)(ws + off); off += (size_t)NN * CAP * 4;
    int* cnt = (int*)(ws + off); off += (size_t)NN * 4;
    u16* x0bf = (u16*)(ws + off); off += (size_t)(NN + 1) * CC * 2;
    u16* yp1 = (u16*)(ws + off); off += (size_t)(NN + 1) * CC * 2;
    u16* yp2 = (u16*)(ws + off); off += (size_t)(NN + 1) * CC * 2;
    u16* yp3 = (u16*)(ws + off); off += (size_t)(NN + 1) * CC * 2;
    u16* Ab = (u16*)(ws + off); off += (size_t)NN * 256 * 2;
    u16* wfrag = (u16*)(ws + off); off += (size_t)288 * 512 * 2;
    float* partials = (float*)(ws + off); off += (size_t)256 * 256 * 4;
    float* coefs = (float*)(ws + off); off += (size_t)4 * 256 * 4;  // [identity, c1, c2, c3]

    k_adj<<<2048, 256, 0, stream>>>(adj, nbr, cnt);
    k_prep<<<1313, 256, 0, stream>>>(W1r, W1s, W2r, W2s, W3r, W3s, Wl, x,
                                     wfrag, x0bf, yp1, yp2, yp3, coefs);

    // layer 1
    k_agg<<<2048, 256, 0, stream>>>(x0bf, coefs, nbr, cnt, Ab);
    k_gemm<<<256, 256, 0, stream>>>(Ab, wfrag, b1, yp1, partials);
    k_stats2<<<1, 256, 0, stream>>>(partials, g1, be1, coefs + 256);
    // layer 2
    k_agg<<<2048, 256, 0, stream>>>(yp1, coefs + 256, nbr, cnt, Ab);
    k_gemm<<<256, 256, 0, stream>>>(Ab, wfrag + 64 * 512, b2, yp2, partials);
    k_stats2<<<1, 256, 0, stream>>>(partials, g2, be2, coefs + 512);
    // layer 3
    k_agg<<<2048, 256, 0, stream>>>(yp2, coefs + 512, nbr, cnt, Ab);
    k_gemm<<<256, 256, 0, stream>>>(Ab, wfrag + 128 * 512, b3, yp3, partials);
    k_stats2<<<1, 256, 0, stream>>>(partials, g3, be3, coefs + 768);

    // final: s, team embeddings, xcat
    k_gfinal<<<256, 256, 0, stream>>>(yp1, yp2, yp3, coefs + 256,
                                      wfrag + 192 * 512, bl, s_out);
    k_team<<<512, 128, 0, stream>>>(yp1, yp2, yp3, coefs + 256, teams, slen, att,
                                    oT, oS, oR);
    k_normcat<<<3072, 256, 0, stream>>>(yp1, yp2, yp3, coefs + 256, xcat);
}